// Round 4
// baseline (313.112 us; speedup 1.0000x reference)
//
#include <hip/hip_runtime.h>
#include <hip/hip_bf16.h>

#define H  32
#define W  32
#define CI 32
#define CO 64
#define NB 8
#define NOUT 32

// d_out float offsets: [w_u | b_u | w_l | b_l]
#define WU_OFF 0
#define BU_OFF (NB * H * W * CI * NOUT)          // 8388608
#define WL_OFF (BU_OFF + NB * NOUT)              // 8388864
#define BL_OFF (WL_OFF + NB * H * W * CI * NOUT) // 16777472

// d_ws layout:
//   [0, 36864)            bf16 A-fragments (2304 uint4)
//   [36864, 38912)        fp32 bias partials bp[16][32]   (fast paths)
//   [36864, 167936)       fp64 bias partials              (fallback path only)
//   [65536, ...)          transposed input T: bf16 [b][pos][n][o], 32 MiB/side
#define KF_UINT4 2304
#define BP_OFF_BYTES 36864
#define T_OFF_BYTES  65536
#define T_SIDE_BYTES (NB * 1024 * 2048 * 2)      // 33554432

typedef __bf16 bf16x8 __attribute__((ext_vector_type(8)));
typedef float  f32x4  __attribute__((ext_vector_type(4)));

__device__ __forceinline__ unsigned int pack_bf16(float lo, float hi) {
    unsigned int ulo = __float_as_uint(lo) + 0x8000u;
    unsigned int uhi = __float_as_uint(hi) + 0x8000u;
    return (uhi & 0xffff0000u) | (ulo >> 16);
}

// Swizzle conv kernel K[3][3][32][64] fp32 -> bf16 A-fragments (HW-verified R1-R3).
// Blocks 9,10 zero the fp32 bias-partial buffer.
__global__ void prep_kernel(const float* __restrict__ K,
                            unsigned int* __restrict__ kws,
                            float* __restrict__ bp) {
    int bx = blockIdx.x, t = threadIdx.x;
    if (bx < 9) {
        int g    = bx * 256 + t;
        int tap  = g >> 8;
        int r    = g & 255;
        int i    = r >> 3;
        int og   = r & 7;
        int c    = og >> 2;
        int quad = og & 3;
        int ih   = i >> 4;
        int lane = quad * 16 + (i & 15);
        int dst  = ((tap * 4 + c * 2 + ih) * 64 + lane) * 4;
        const float4* src = (const float4*)(K + (size_t)g * 8);
        float4 f0 = src[0];
        float4 f1 = src[1];
        kws[dst + 0] = pack_bf16(f0.x, f0.y);
        kws[dst + 1] = pack_bf16(f0.z, f0.w);
        kws[dst + 2] = pack_bf16(f1.x, f1.y);
        kws[dst + 3] = pack_bf16(f1.z, f1.w);
    } else {
        bp[(bx - 9) * 256 + t] = 0.f;
    }
}

// Pass 1: transpose one side's w [b][pos][o][n] fp32 -> T [b][pos][n][o] bf16,
// fusing the bias einsum. Reads and the per-line decomposition are exactly
// coalesced: line [o][*] is read by exactly one half-wave instruction.
__global__ __launch_bounds__(256)
void transpose_kernel(const float* __restrict__ in,
                      uint4* __restrict__ T,
                      const float* __restrict__ bias,
                      float* __restrict__ bp) {   // bp: 8*32 floats (this side)
    __shared__ float bias_s[CO];
    __shared__ float bred[8][32];
    int t = threadIdx.x;
    if (t < CO) bias_s[t] = bias[t];
    __syncthreads();

    int blk = blockIdx.x;            // 0..8191
    int b   = blk >> 10;
    int pos = blk & 1023;
    const float* p = in + ((size_t)b * 1024 + pos) * 2048;
    int n  = t & 31;
    int og = t >> 5;                 // o-octet 0..7
    int o0 = og * 8;

    float v[8];
#pragma unroll
    for (int j = 0; j < 8; j++)
        v[j] = p[(size_t)(o0 + j) * NOUT + n];   // coalesced: 128 B per half-wave

    float s = 0.f;
#pragma unroll
    for (int j = 0; j < 8; j++)
        s = fmaf(v[j], bias_s[o0 + j], s);

    uint4 u;
    u.x = pack_bf16(v[0], v[1]);
    u.y = pack_bf16(v[2], v[3]);
    u.z = pack_bf16(v[4], v[5]);
    u.w = pack_bf16(v[6], v[7]);
    T[((size_t)b * 1024 + pos) * 256 + n * 8 + og] = u;

    bred[og][n] = s;
    __syncthreads();
    if (t < 32) {
        float ss = 0.f;
#pragma unroll
        for (int g = 0; g < 8; g++) ss += bred[g][t];
        atomicAdd(&bp[b * 32 + t], ss);
    }
}

// Pass 2: conv from transposed bf16. One wave per (b,h,w); B-fragments are
// single dwordx4 loads (no repack). A/C-D maps identical to verified R3 conv.
__global__ __launch_bounds__(256, 4)
void conv_t_kernel(const uint4* __restrict__ T,
                   const uint4* __restrict__ kws,
                   float* __restrict__ wout_base) {
    __shared__ uint4 kf[KF_UINT4];
    int t = threadIdx.x;
#pragma unroll
    for (int k = 0; k < 9; k++) kf[t + 256 * k] = kws[t + 256 * k];
    __syncthreads();

    int bx   = blockIdx.x;           // 0..2047
    int b    = bx >> 8;
    int slot = bx & 255;
    int h    = slot >> 3;
    int wq   = slot & 7;
    int wave = t >> 6;
    int lane = t & 63;
    int w    = wq * 4 + wave;
    int n16  = lane & 15;
    int quad = lane >> 4;

    const uint4* Tb = T + (size_t)b * 1024 * 256;
    f32x4 acc[2][2] = {};
    const bf16x8* kfp = (const bf16x8*)kf;

#pragma unroll
    for (int kh = 0; kh < 3; kh++) {
        int hi = h + 1 - kh;
        if (hi < 0 || hi >= H) continue;
#pragma unroll
        for (int kw = 0; kw < 3; kw++) {
            int wi = w + 1 - kw;
            if (wi < 0 || wi >= W) continue;
            int tap = kh * 3 + kw;
            const uint4* Tp = Tb + (size_t)(hi * W + wi) * 256;
#pragma unroll
            for (int c = 0; c < 2; c++) {
                union { uint4 u; bf16x8 v; } b0, b1;
                b0.u = Tp[n16 * 8 + c * 4 + quad];
                b1.u = Tp[(n16 + 16) * 8 + c * 4 + quad];
                bf16x8 a0 = kfp[(tap * 4 + c * 2 + 0) * 64 + lane];
                bf16x8 a1 = kfp[(tap * 4 + c * 2 + 1) * 64 + lane];
                acc[0][0] = __builtin_amdgcn_mfma_f32_16x16x32_bf16(a0, b0.v, acc[0][0], 0, 0, 0);
                acc[0][1] = __builtin_amdgcn_mfma_f32_16x16x32_bf16(a0, b1.v, acc[0][1], 0, 0, 0);
                acc[1][0] = __builtin_amdgcn_mfma_f32_16x16x32_bf16(a1, b0.v, acc[1][0], 0, 0, 0);
                acc[1][1] = __builtin_amdgcn_mfma_f32_16x16x32_bf16(a1, b1.v, acc[1][1], 0, 0, 0);
            }
        }
    }

    float* wout = wout_base + (size_t)b * (H * W * CI * NOUT)
                + (size_t)((h * W + w) * CI) * NOUT;
#pragma unroll
    for (int ih = 0; ih < 2; ih++)
#pragma unroll
        for (int nh = 0; nh < 2; nh++)
#pragma unroll
            for (int r = 0; r < 4; r++) {
                int i = ih * 16 + quad * 4 + r;
                int n = nh * 16 + n16;
                wout[i * NOUT + n] = acc[ih][nh][r];
            }
}

// Fast-path bias finalize: b = b_in + bp
__global__ void bias_final32_kernel(const float* __restrict__ bp,
                                    const float* __restrict__ bu,
                                    const float* __restrict__ bl,
                                    float* __restrict__ out) {
    int sb = blockIdx.x;             // 0..15
    int t  = threadIdx.x;
    if (t >= NOUT) return;
    int side = sb >> 3, b = sb & 7;
    const float* bb = side ? bl : bu;
    out[(side ? BL_OFF : BU_OFF) + b * NOUT + t] =
        bb[b * NOUT + t] + bp[sb * 32 + t];
}

// ---------------- fallback path (proven R3 kernels) ----------------
__global__ __launch_bounds__(256, 4)
void conv_bwd_kernel(const float* __restrict__ wu,
                     const float* __restrict__ wl,
                     const uint4* __restrict__ kws,
                     float* __restrict__ out) {
    __shared__ uint4 kf[KF_UINT4];
    int t = threadIdx.x;
#pragma unroll
    for (int k = 0; k < 9; k++) kf[t + 256 * k] = kws[t + 256 * k];
    __syncthreads();

    int bx   = blockIdx.x;
    int side = bx >> 11;
    int rem  = bx & 2047;
    int b    = rem >> 8;
    int slot = rem & 255;
    int h    = slot >> 3;
    int wq   = slot & 7;
    int wave = t >> 6;
    int lane = t & 63;
    int w    = wq * 4 + wave;
    int n16  = lane & 15;
    int quad = lane >> 4;

    const float* in  = side ? wl : wu;
    const float* inb = in + (size_t)b * (H * W * CO * NOUT);
    f32x4 acc[2][2] = {};
    const bf16x8* kfp = (const bf16x8*)kf;

#pragma unroll
    for (int kh = 0; kh < 3; kh++) {
        int hi = h + 1 - kh;
        if (hi < 0 || hi >= H) continue;
#pragma unroll
        for (int kw = 0; kw < 3; kw++) {
            int wi = w + 1 - kw;
            if (wi < 0 || wi >= W) continue;
            int tap = kh * 3 + kw;
            const float* p = inb + (size_t)((hi * W + wi) * CO) * NOUT;
#pragma unroll
            for (int c = 0; c < 2; c++) {
                int ob = c * 32 + quad * 8;
                const float* p0 = p + ob * NOUT + n16;
                float v0[8], v1[8];
#pragma unroll
                for (int j = 0; j < 8; j++) {
                    v0[j] = p0[j * NOUT];
                    v1[j] = p0[j * NOUT + 16];
                }
                union { unsigned int u[4]; bf16x8 v; } b0, b1;
#pragma unroll
                for (int j = 0; j < 4; j++) {
                    b0.u[j] = pack_bf16(v0[2 * j], v0[2 * j + 1]);
                    b1.u[j] = pack_bf16(v1[2 * j], v1[2 * j + 1]);
                }
                bf16x8 a0 = kfp[(tap * 4 + c * 2 + 0) * 64 + lane];
                bf16x8 a1 = kfp[(tap * 4 + c * 2 + 1) * 64 + lane];
                acc[0][0] = __builtin_amdgcn_mfma_f32_16x16x32_bf16(a0, b0.v, acc[0][0], 0, 0, 0);
                acc[0][1] = __builtin_amdgcn_mfma_f32_16x16x32_bf16(a0, b1.v, acc[0][1], 0, 0, 0);
                acc[1][0] = __builtin_amdgcn_mfma_f32_16x16x32_bf16(a1, b0.v, acc[1][0], 0, 0, 0);
                acc[1][1] = __builtin_amdgcn_mfma_f32_16x16x32_bf16(a1, b1.v, acc[1][1], 0, 0, 0);
            }
        }
    }

    float* wout = out + (side ? WL_OFF : WU_OFF)
                + (size_t)b * (H * W * CI * NOUT)
                + (size_t)((h * W + w) * CI) * NOUT;
#pragma unroll
    for (int ih = 0; ih < 2; ih++)
#pragma unroll
        for (int nh = 0; nh < 2; nh++)
#pragma unroll
            for (int r = 0; r < 4; r++) {
                int i = ih * 16 + quad * 4 + r;
                int n = nh * 16 + n16;
                wout[i * NOUT + n] = acc[ih][nh][r];
            }
}

__global__ __launch_bounds__(256)
void bias_part_kernel(const float* __restrict__ wu,
                      const float* __restrict__ wl,
                      const float* __restrict__ bias,
                      double* __restrict__ bpart) {
    __shared__ double sred[8][32];
    __shared__ float bias_s[CO];
    int t = threadIdx.x;
    if (t < CO) bias_s[t] = bias[t];
    __syncthreads();

    int blk  = blockIdx.x;
    int sb   = blk >> 5;
    int h    = blk & 31;
    int side = sb >> 3, b = sb & 7;
    const float* in = (side ? wl : wu)
                    + (size_t)b * (H * W * CO * NOUT)
                    + (size_t)h * (W * CO * NOUT);
    int lane = t & 31;
    int g    = t >> 5;
    double acc = 0.0;
    for (int f = g; f < W * CO; f += 8)
        acc += (double)in[(size_t)f * NOUT + lane] * (double)bias_s[f & 63];
    sred[g][lane] = acc;
    __syncthreads();
    if (t < 32) {
        double s = 0.0;
#pragma unroll
        for (int g2 = 0; g2 < 8; g2++) s += sred[g2][t];
        bpart[(size_t)blk * 32 + t] = s;
    }
}

__global__ void bias_final64_kernel(const double* __restrict__ bpart,
                                    const float* __restrict__ bu,
                                    const float* __restrict__ bl,
                                    float* __restrict__ out) {
    int sb = blockIdx.x;
    int t  = threadIdx.x;
    if (t >= NOUT) return;
    double s = 0.0;
    for (int h = 0; h < 32; h++) s += bpart[(size_t)(sb * 32 + h) * 32 + t];
    int side = sb >> 3, b = sb & 7;
    const float* bb = side ? bl : bu;
    out[(side ? BL_OFF : BU_OFF) + b * NOUT + t] =
        (float)((double)bb[b * NOUT + t] + s);
}

extern "C" void kernel_launch(void* const* d_in, const int* in_sizes, int n_in,
                              void* d_out, int out_size, void* d_ws, size_t ws_size,
                              hipStream_t stream) {
    const float* wu   = (const float*)d_in[0];
    const float* bu   = (const float*)d_in[1];
    const float* wl   = (const float*)d_in[2];
    const float* bl   = (const float*)d_in[3];
    const float* K    = (const float*)d_in[4];
    const float* bias = (const float*)d_in[5];
    float* out = (float*)d_out;
    unsigned int* kws = (unsigned int*)d_ws;
    float*  bp    = (float*)((char*)d_ws + BP_OFF_BYTES);
    double* bpart = (double*)((char*)d_ws + BP_OFF_BYTES);
    uint4*  T0    = (uint4*)((char*)d_ws + T_OFF_BYTES);
    uint4*  T1    = (uint4*)((char*)d_ws + T_OFF_BYTES + T_SIDE_BYTES);

    const size_t full_need = (size_t)T_OFF_BYTES + 2 * (size_t)T_SIDE_BYTES;
    const size_t half_need = (size_t)T_OFF_BYTES + (size_t)T_SIDE_BYTES;

    prep_kernel<<<dim3(11), dim3(256), 0, stream>>>(K, kws, bp);

    if (ws_size >= full_need) {
        transpose_kernel<<<dim3(8192), dim3(256), 0, stream>>>(wu, T0, bias, bp);
        transpose_kernel<<<dim3(8192), dim3(256), 0, stream>>>(wl, T1, bias, bp + 256);
        conv_t_kernel<<<dim3(2048), dim3(256), 0, stream>>>(T0, (const uint4*)d_ws, out + WU_OFF);
        conv_t_kernel<<<dim3(2048), dim3(256), 0, stream>>>(T1, (const uint4*)d_ws, out + WL_OFF);
        bias_final32_kernel<<<dim3(16), dim3(64), 0, stream>>>(bp, bu, bl, out);
    } else if (ws_size >= half_need) {
        transpose_kernel<<<dim3(8192), dim3(256), 0, stream>>>(wu, T0, bias, bp);
        conv_t_kernel<<<dim3(2048), dim3(256), 0, stream>>>(T0, (const uint4*)d_ws, out + WU_OFF);
        transpose_kernel<<<dim3(8192), dim3(256), 0, stream>>>(wl, T0, bias, bp + 256);
        conv_t_kernel<<<dim3(2048), dim3(256), 0, stream>>>(T0, (const uint4*)d_ws, out + WL_OFF);
        bias_final32_kernel<<<dim3(16), dim3(64), 0, stream>>>(bp, bu, bl, out);
    } else {
        conv_bwd_kernel<<<dim3(4096), dim3(256), 0, stream>>>(wu, wl, (const uint4*)d_ws, out);
        bias_part_kernel<<<dim3(512), dim3(256), 0, stream>>>(wu, wl, bias, bpart);
        bias_final64_kernel<<<dim3(16), dim3(64), 0, stream>>>(bpart, bu, bl, out);
    }
}

// Round 5
// 244.956 us; speedup vs baseline: 1.2782x; 1.2782x over previous
//
#include <hip/hip_runtime.h>
#include <hip/hip_bf16.h>

#define H  32
#define W  32
#define CI 32
#define CO 64
#define NB 8
#define NOUT 32

// d_out float offsets: [w_u | b_u | w_l | b_l]
#define WU_OFF 0
#define BU_OFF (NB * H * W * CI * NOUT)          // 8388608
#define WL_OFF (BU_OFF + NB * NOUT)              // 8388864
#define BL_OFF (WL_OFF + NB * H * W * CI * NOUT) // 16777472

// d_ws layout:
//   [0, 36864)            bf16 A-fragments (2304 uint4)
//   [36864, 38912)        fp32 bias partials bp[16][32]   (fast paths)
//   [36864, 167936)       fp64 bias partials              (fallback path only)
//   [65536, ...)          transposed input T: bf16 [b][pos][og][n], 32 MiB/side
#define KF_UINT4 2304
#define BP_OFF_BYTES 36864
#define T_OFF_BYTES  65536
#define T_SIDE_BYTES (NB * 1024 * 2048 * 2)      // 33554432

typedef __bf16 bf16x8 __attribute__((ext_vector_type(8)));
typedef float  f32x4  __attribute__((ext_vector_type(4)));

__device__ __forceinline__ unsigned int pack_bf16(float lo, float hi) {
    unsigned int ulo = __float_as_uint(lo) + 0x8000u;
    unsigned int uhi = __float_as_uint(hi) + 0x8000u;
    return (uhi & 0xffff0000u) | (ulo >> 16);
}

// Swizzle conv kernel K[3][3][32][64] fp32 -> bf16 A-fragments (HW-verified R1-R4).
// Blocks 9,10 zero the fp32 bias-partial buffer.
__global__ void prep_kernel(const float* __restrict__ K,
                            unsigned int* __restrict__ kws,
                            float* __restrict__ bp) {
    int bx = blockIdx.x, t = threadIdx.x;
    if (bx < 9) {
        int g    = bx * 256 + t;
        int tap  = g >> 8;
        int r    = g & 255;
        int i    = r >> 3;
        int og   = r & 7;
        int c    = og >> 2;
        int quad = og & 3;
        int ih   = i >> 4;
        int lane = quad * 16 + (i & 15);
        int dst  = ((tap * 4 + c * 2 + ih) * 64 + lane) * 4;
        const float4* src = (const float4*)(K + (size_t)g * 8);
        float4 f0 = src[0];
        float4 f1 = src[1];
        kws[dst + 0] = pack_bf16(f0.x, f0.y);
        kws[dst + 1] = pack_bf16(f0.z, f0.w);
        kws[dst + 2] = pack_bf16(f1.x, f1.y);
        kws[dst + 3] = pack_bf16(f1.z, f1.w);
    } else {
        bp[(bx - 9) * 256 + t] = 0.f;
    }
}

// Pass 1 (both sides in one launch at grid 16384; single side at grid 8192):
// transpose w [b][pos][o][n] fp32 -> T [b][pos][og][n] bf16 (uint4 = 8 bf16
// along o at fixed n), fusing the bias einsum. Reads: 2x128 B segments per
// wave-instr. Stores: T[base + threadIdx.x] — perfectly coalesced, no LDS.
__global__ __launch_bounds__(256)
void transpose_kernel(const float* __restrict__ in0,
                      const float* __restrict__ in1,
                      uint4* __restrict__ Tb0,
                      uint4* __restrict__ Tb1,
                      const float* __restrict__ bias,
                      float* __restrict__ bp) {   // bp[side][8][32]
    __shared__ float bias_s[CO];
    __shared__ float bred[8][32];
    int t = threadIdx.x;
    if (t < CO) bias_s[t] = bias[t];
    __syncthreads();

    int blk  = blockIdx.x;
    int side = blk >> 13;            // 0 when grid == 8192
    int rem  = blk & 8191;
    int b    = rem >> 10;
    int pos  = rem & 1023;
    const float* p = (side ? in1 : in0) + ((size_t)b * 1024 + pos) * 2048;
    uint4* T = side ? Tb1 : Tb0;
    int n  = t & 31;
    int og = t >> 5;                 // o-octet 0..7
    int o0 = og * 8;

    float v[8];
#pragma unroll
    for (int j = 0; j < 8; j++)
        v[j] = p[(o0 + j) * NOUT + n];   // coalesced: 128 B per half-wave per j

    float s = 0.f;
#pragma unroll
    for (int j = 0; j < 8; j++)
        s = fmaf(v[j], bias_s[o0 + j], s);

    uint4 u;
    u.x = pack_bf16(v[0], v[1]);
    u.y = pack_bf16(v[2], v[3]);
    u.z = pack_bf16(v[4], v[5]);
    u.w = pack_bf16(v[6], v[7]);
    T[((size_t)b * 1024 + pos) * 256 + t] = u;   // og*32 + n == t

    bred[og][n] = s;
    __syncthreads();
    if (t < 32) {
        float ss = 0.f;
#pragma unroll
        for (int g = 0; g < 8; g++) ss += bred[g][t];
        atomicAdd(&bp[side * 256 + b * 32 + t], ss);
    }
}

// Pass 2 (both sides at grid 4096; single side at grid 2048): conv from
// transposed bf16. B-fragment = Tp[(c*4+quad)*32 + n16]: 16 consecutive uint4
// per quarter-wave -> coalesced dwordx4. A/C-D maps identical to verified R3.
__global__ __launch_bounds__(256, 4)
void conv_t_kernel(const uint4* __restrict__ Tb0,
                   const uint4* __restrict__ Tb1,
                   const uint4* __restrict__ kws,
                   float* __restrict__ out0,
                   float* __restrict__ out1) {
    __shared__ uint4 kf[KF_UINT4];
    int t = threadIdx.x;
#pragma unroll
    for (int k = 0; k < 9; k++) kf[t + 256 * k] = kws[t + 256 * k];
    __syncthreads();

    int bx   = blockIdx.x;
    int side = bx >> 11;             // 0 when grid == 2048
    int rem  = bx & 2047;
    int b    = rem >> 8;
    int slot = rem & 255;
    int h    = slot >> 3;
    int wq   = slot & 7;
    int wave = t >> 6;
    int lane = t & 63;
    int w    = wq * 4 + wave;
    int n16  = lane & 15;
    int quad = lane >> 4;

    const uint4* Tb = (side ? Tb1 : Tb0) + (size_t)b * 1024 * 256;
    f32x4 acc[2][2] = {};
    const bf16x8* kfp = (const bf16x8*)kf;

#pragma unroll
    for (int kh = 0; kh < 3; kh++) {
        int hi = h + 1 - kh;
        if (hi < 0 || hi >= H) continue;
#pragma unroll
        for (int kw = 0; kw < 3; kw++) {
            int wi = w + 1 - kw;
            if (wi < 0 || wi >= W) continue;
            int tap = kh * 3 + kw;
            const uint4* Tp = Tb + (size_t)(hi * W + wi) * 256;
#pragma unroll
            for (int c = 0; c < 2; c++) {
                union { uint4 u; bf16x8 v; } b0, b1;
                b0.u = Tp[(c * 4 + quad) * 32 + n16];
                b1.u = Tp[(c * 4 + quad) * 32 + n16 + 16];
                bf16x8 a0 = kfp[(tap * 4 + c * 2 + 0) * 64 + lane];
                bf16x8 a1 = kfp[(tap * 4 + c * 2 + 1) * 64 + lane];
                acc[0][0] = __builtin_amdgcn_mfma_f32_16x16x32_bf16(a0, b0.v, acc[0][0], 0, 0, 0);
                acc[0][1] = __builtin_amdgcn_mfma_f32_16x16x32_bf16(a0, b1.v, acc[0][1], 0, 0, 0);
                acc[1][0] = __builtin_amdgcn_mfma_f32_16x16x32_bf16(a1, b0.v, acc[1][0], 0, 0, 0);
                acc[1][1] = __builtin_amdgcn_mfma_f32_16x16x32_bf16(a1, b1.v, acc[1][1], 0, 0, 0);
            }
        }
    }

    float* wout = (side ? out1 : out0)
                + (size_t)b * (H * W * CI * NOUT)
                + (size_t)((h * W + w) * CI) * NOUT;
#pragma unroll
    for (int ih = 0; ih < 2; ih++)
#pragma unroll
        for (int nh = 0; nh < 2; nh++)
#pragma unroll
            for (int r = 0; r < 4; r++) {
                int i = ih * 16 + quad * 4 + r;
                int n = nh * 16 + n16;
                wout[i * NOUT + n] = acc[ih][nh][r];
            }
}

// Fast-path bias finalize: b = b_in + bp
__global__ void bias_final32_kernel(const float* __restrict__ bp,
                                    const float* __restrict__ bu,
                                    const float* __restrict__ bl,
                                    float* __restrict__ out) {
    int sb = blockIdx.x;             // 0..15
    int t  = threadIdx.x;
    if (t >= NOUT) return;
    int side = sb >> 3, b = sb & 7;
    const float* bb = side ? bl : bu;
    out[(side ? BL_OFF : BU_OFF) + b * NOUT + t] =
        bb[b * NOUT + t] + bp[sb * 32 + t];
}

// ---------------- fallback path (proven R3 kernels) ----------------
__global__ __launch_bounds__(256, 4)
void conv_bwd_kernel(const float* __restrict__ wu,
                     const float* __restrict__ wl,
                     const uint4* __restrict__ kws,
                     float* __restrict__ out) {
    __shared__ uint4 kf[KF_UINT4];
    int t = threadIdx.x;
#pragma unroll
    for (int k = 0; k < 9; k++) kf[t + 256 * k] = kws[t + 256 * k];
    __syncthreads();

    int bx   = blockIdx.x;
    int side = bx >> 11;
    int rem  = bx & 2047;
    int b    = rem >> 8;
    int slot = rem & 255;
    int h    = slot >> 3;
    int wq   = slot & 7;
    int wave = t >> 6;
    int lane = t & 63;
    int w    = wq * 4 + wave;
    int n16  = lane & 15;
    int quad = lane >> 4;

    const float* in  = side ? wl : wu;
    const float* inb = in + (size_t)b * (H * W * CO * NOUT);
    f32x4 acc[2][2] = {};
    const bf16x8* kfp = (const bf16x8*)kf;

#pragma unroll
    for (int kh = 0; kh < 3; kh++) {
        int hi = h + 1 - kh;
        if (hi < 0 || hi >= H) continue;
#pragma unroll
        for (int kw = 0; kw < 3; kw++) {
            int wi = w + 1 - kw;
            if (wi < 0 || wi >= W) continue;
            int tap = kh * 3 + kw;
            const float* p = inb + (size_t)((hi * W + wi) * CO) * NOUT;
#pragma unroll
            for (int c = 0; c < 2; c++) {
                int ob = c * 32 + quad * 8;
                const float* p0 = p + ob * NOUT + n16;
                float v0[8], v1[8];
#pragma unroll
                for (int j = 0; j < 8; j++) {
                    v0[j] = p0[j * NOUT];
                    v1[j] = p0[j * NOUT + 16];
                }
                union { unsigned int u[4]; bf16x8 v; } b0, b1;
#pragma unroll
                for (int j = 0; j < 4; j++) {
                    b0.u[j] = pack_bf16(v0[2 * j], v0[2 * j + 1]);
                    b1.u[j] = pack_bf16(v1[2 * j], v1[2 * j + 1]);
                }
                bf16x8 a0 = kfp[(tap * 4 + c * 2 + 0) * 64 + lane];
                bf16x8 a1 = kfp[(tap * 4 + c * 2 + 1) * 64 + lane];
                acc[0][0] = __builtin_amdgcn_mfma_f32_16x16x32_bf16(a0, b0.v, acc[0][0], 0, 0, 0);
                acc[0][1] = __builtin_amdgcn_mfma_f32_16x16x32_bf16(a0, b1.v, acc[0][1], 0, 0, 0);
                acc[1][0] = __builtin_amdgcn_mfma_f32_16x16x32_bf16(a1, b0.v, acc[1][0], 0, 0, 0);
                acc[1][1] = __builtin_amdgcn_mfma_f32_16x16x32_bf16(a1, b1.v, acc[1][1], 0, 0, 0);
            }
        }
    }

    float* wout = out + (side ? WL_OFF : WU_OFF)
                + (size_t)b * (H * W * CI * NOUT)
                + (size_t)((h * W + w) * CI) * NOUT;
#pragma unroll
    for (int ih = 0; ih < 2; ih++)
#pragma unroll
        for (int nh = 0; nh < 2; nh++)
#pragma unroll
            for (int r = 0; r < 4; r++) {
                int i = ih * 16 + quad * 4 + r;
                int n = nh * 16 + n16;
                wout[i * NOUT + n] = acc[ih][nh][r];
            }
}

__global__ __launch_bounds__(256)
void bias_part_kernel(const float* __restrict__ wu,
                      const float* __restrict__ wl,
                      const float* __restrict__ bias,
                      double* __restrict__ bpart) {
    __shared__ double sred[8][32];
    __shared__ float bias_s[CO];
    int t = threadIdx.x;
    if (t < CO) bias_s[t] = bias[t];
    __syncthreads();

    int blk  = blockIdx.x;
    int sb   = blk >> 5;
    int h    = blk & 31;
    int side = sb >> 3, b = sb & 7;
    const float* in = (side ? wl : wu)
                    + (size_t)b * (H * W * CO * NOUT)
                    + (size_t)h * (W * CO * NOUT);
    int lane = t & 31;
    int g    = t >> 5;
    double acc = 0.0;
    for (int f = g; f < W * CO; f += 8)
        acc += (double)in[(size_t)f * NOUT + lane] * (double)bias_s[f & 63];
    sred[g][lane] = acc;
    __syncthreads();
    if (t < 32) {
        double s = 0.0;
#pragma unroll
        for (int g2 = 0; g2 < 8; g2++) s += sred[g2][t];
        bpart[(size_t)blk * 32 + t] = s;
    }
}

__global__ void bias_final64_kernel(const double* __restrict__ bpart,
                                    const float* __restrict__ bu,
                                    const float* __restrict__ bl,
                                    float* __restrict__ out) {
    int sb = blockIdx.x;
    int t  = threadIdx.x;
    if (t >= NOUT) return;
    double s = 0.0;
    for (int h = 0; h < 32; h++) s += bpart[(size_t)(sb * 32 + h) * 32 + t];
    int side = sb >> 3, b = sb & 7;
    const float* bb = side ? bl : bu;
    out[(side ? BL_OFF : BU_OFF) + b * NOUT + t] =
        (float)((double)bb[b * NOUT + t] + s);
}

extern "C" void kernel_launch(void* const* d_in, const int* in_sizes, int n_in,
                              void* d_out, int out_size, void* d_ws, size_t ws_size,
                              hipStream_t stream) {
    const float* wu   = (const float*)d_in[0];
    const float* bu   = (const float*)d_in[1];
    const float* wl   = (const float*)d_in[2];
    const float* bl   = (const float*)d_in[3];
    const float* K    = (const float*)d_in[4];
    const float* bias = (const float*)d_in[5];
    float* out = (float*)d_out;
    unsigned int* kws = (unsigned int*)d_ws;
    float*  bp    = (float*)((char*)d_ws + BP_OFF_BYTES);
    double* bpart = (double*)((char*)d_ws + BP_OFF_BYTES);
    uint4*  T0    = (uint4*)((char*)d_ws + T_OFF_BYTES);
    uint4*  T1    = (uint4*)((char*)d_ws + T_OFF_BYTES + T_SIDE_BYTES);

    const size_t full_need = (size_t)T_OFF_BYTES + 2 * (size_t)T_SIDE_BYTES;
    const size_t half_need = (size_t)T_OFF_BYTES + (size_t)T_SIDE_BYTES;

    prep_kernel<<<dim3(11), dim3(256), 0, stream>>>(K, kws, bp);

    if (ws_size >= full_need) {
        transpose_kernel<<<dim3(16384), dim3(256), 0, stream>>>(wu, wl, T0, T1, bias, bp);
        conv_t_kernel<<<dim3(4096), dim3(256), 0, stream>>>(T0, T1, (const uint4*)d_ws,
                                                            out + WU_OFF, out + WL_OFF);
        bias_final32_kernel<<<dim3(16), dim3(64), 0, stream>>>(bp, bu, bl, out);
    } else if (ws_size >= half_need) {
        transpose_kernel<<<dim3(8192), dim3(256), 0, stream>>>(wu, wu, T0, T0, bias, bp);
        conv_t_kernel<<<dim3(2048), dim3(256), 0, stream>>>(T0, T0, (const uint4*)d_ws,
                                                            out + WU_OFF, out + WU_OFF);
        transpose_kernel<<<dim3(8192), dim3(256), 0, stream>>>(wl, wl, T0, T0, bias, bp + 256);
        conv_t_kernel<<<dim3(2048), dim3(256), 0, stream>>>(T0, T0, (const uint4*)d_ws,
                                                            out + WL_OFF, out + WL_OFF);
        bias_final32_kernel<<<dim3(16), dim3(64), 0, stream>>>(bp, bu, bl, out);
    } else {
        conv_bwd_kernel<<<dim3(4096), dim3(256), 0, stream>>>(wu, wl, (const uint4*)d_ws, out);
        bias_part_kernel<<<dim3(512), dim3(256), 0, stream>>>(wu, wl, bias, bpart);
        bias_final64_kernel<<<dim3(16), dim3(64), 0, stream>>>(bpart, bu, bl, out);
    }
}